// Round 13
// baseline (121.658 us; speedup 1.0000x reference)
//
#include <hip/hip_runtime.h>

// MinEuclideanDistBlock: x(32,8,4096) f32, shapelets(8,128,64) f32 -> out(32,1,128) f32
// out[b,k] = min_w sum_c sqrt( xnorm[b,c,w] + snorm[c,k] - 2*sum_s x[b,c,w+s]*h[c,k,s] )
//
// R14 -> R15 (post-mortem: occupancy does NOT predict time - 18%/26%/27%/34% all give
// 57-89us; the barrier-locked c-loop has a ~57us floor at every residency. ~60% of
// wall is stall at the per-c-iter __syncthreads + vmcnt(0) drain + slowest-wave jitter.
// Key fact: per-channel sqrt means channels combine by ADDITION only -> a wave can own
// a K-slice and run the whole c-loop privately):
//  - ZERO barriers in the main loop. Wave = one K-quarter (32 shapelets) x all 128
//    windows; dist[8][2][4]=64 regs; 32 MFMA/c-iter (R5's amortization).
//  - Per-wave private staging: Bs[wv] 4KB SINGLE-buffered (B-frags consumed into 16
//    regs at iter top, then DMA next c into same buffer; explicit lgkmcnt(0) orders
//    read-before-overwrite, vmcnt(0) at iter top drains the one-phase-old DMA).
//    Xr[wv][2] 3.2KB double-buffered, self-staged with f2bf in 3 reg-scoped batches.
//  - Prologue (xnorm/snorm shared) keeps the ONE barrier. Waves then free-run and
//    desynchronize -> DMA/VALU/MFMA of different waves overlap on the CU.
//  - LDS 49KB; VGPR est ~122 <= 128 budget of (256,2). grid 32x32 (R5's block count).
//  - Tripwires: WRITE_SIZE >> 2MB = spill -> fallback is dist[4][2][4] (64w x 32k).

typedef short short8 __attribute__((ext_vector_type(8)));
typedef float f32x4 __attribute__((ext_vector_type(4)));

constexpr int Bn = 32, Cn = 8, Ln = 4096, Kn = 128, Sn = 64;
constexpr int Wn = Ln - Sn + 1;          // 4033
constexpr int WT = 128;                  // windows per block (all waves share)
constexpr int NWT = (Wn + WT - 1) / WT;  // 32
constexpr int BDIM = 256;                // 4 waves = 4 K-quarters
constexpr int XRS = 200;                 // Xr row stride (elems); 400B, 100w = 4 mod 32
constexpr int PPR = 96;                  // pairs per Xr row
constexpr int PAIRS = 8 * PPR;           // 768 pairs per channel (per wave copy)

typedef const __attribute__((address_space(1))) unsigned int gas_u32;
typedef __attribute__((address_space(3))) unsigned int las_u32;

__device__ __forceinline__ unsigned int f2bf(float f) {
  unsigned int u = __float_as_uint(f);
  u += 0x7FFFu + ((u >> 16) & 1u);       // round-to-nearest-even
  return u >> 16;
}

// ws layout: [0, 128KB): ushort hbf[C][K][S] = bf16(-2*h), byte-swizzled ^((k&7)<<4)
//            [128KB, +4KB): float snorm[C][K]
__global__ void prep_kernel(const float* __restrict__ sh,
                            unsigned int* __restrict__ out,
                            unsigned short* __restrict__ hbf,
                            float* __restrict__ snorm) {
  int gid = blockIdx.x * blockDim.x + threadIdx.x;  // 0..4095
  out[gid] = 0x7F7FFFFFu;                           // FLT_MAX bits (Bn*Kn == 4096)
  if (gid < Cn * Kn) {
    const float4* row = (const float4*)(sh + (size_t)gid * Sn);
    char* rowb = (char*)hbf + (size_t)gid * (Sn * 2);   // 128B row
    const unsigned int sw = (gid & 7u) << 4;            // (k&7)<<4 byte swizzle
    float a = 0.f;
    #pragma unroll
    for (int i = 0; i < 16; ++i) {
      float4 v = row[i];
      a += v.x * v.x + v.y * v.y + v.z * v.z + v.w * v.w;
      unsigned int p0 = f2bf(-2.f * v.x) | (f2bf(-2.f * v.y) << 16);
      unsigned int p1 = f2bf(-2.f * v.z) | (f2bf(-2.f * v.w) << 16);
      *(uint2*)(rowb + ((8u * i) ^ sw)) = make_uint2(p0, p1);  // stays 8B-aligned
    }
    snorm[gid] = a;
  }
}

__launch_bounds__(BDIM, 2)
__global__ void med_kernel(const float* __restrict__ x,
                           const unsigned short* __restrict__ hbf,
                           const float* __restrict__ snorm,
                           unsigned int* __restrict__ out) {
  // per-wave private staging regions
  __shared__ __align__(16) unsigned short Xr[4][2][8 * XRS];  // 4 x 2 x 3.2KB = 25.6KB
  __shared__ __align__(16) unsigned short Bs[4][32 * Sn];     // 4 x 4KB (single-buf)
  __shared__ __align__(16) float xnormC[Cn * WT];             // 4KB (shared, prologue)
  __shared__ __align__(16) float snormC[Cn * Kn];             // 4KB (shared, prologue)

  const int tid  = threadIdx.x;
  const int b    = blockIdx.y;
  const int w0   = blockIdx.x * WT;
  const int lane = tid & 63;
  const int wv   = tid >> 6;     // wave 0..3 = K-quarter
  const int quad = lane >> 4;    // 0..3
  const int n16  = lane & 15;
  const int kq   = wv;           // this wave's shapelet quarter: k in [kq*32, kq*32+32)

  const float* xb = x + (size_t)b * Cn * Ln;

  // ---- per-wave B staging: 4KB K-quarter slice via linear DMA (pre-swizzled hbf) ----
  auto stage_b = [&](int c) {
    const char* src = (const char*)hbf + ((size_t)c * Kn + kq * 32) * (Sn * 2);
    char* dst = (char*)&Bs[wv][0];
    #pragma unroll
    for (int rep = 0; rep < 4; ++rep) {
      int q16 = lane * 16 + rep * 1024;   // wave-uniform base + lane*16
      __builtin_amdgcn_global_load_lds((gas_u32*)(src + q16), (las_u32*)(dst + q16),
                                       16, 0, 0);
    }
  };

  // ---- per-wave X staging: 768 bf16-pairs in 3 reg-scoped batches (f2bf on the fly) ----
  auto stage_x = [&](int c, int xbuf) {
    const float* xc = xb + (size_t)c * Ln;
    #pragma unroll
    for (int bt = 0; bt < 3; ++bt) {
      float a[4][2];
      #pragma unroll
      for (int sub = 0; sub < 4; ++sub) {
        int pid = lane + (bt * 4 + sub) * 64;   // 0..767
        int r = pid / PPR, p = pid - r * PPR;
        int i0 = w0 + r + 2 * p;
        a[sub][0] = (i0 < Ln) ? xc[i0] : 0.f;
        a[sub][1] = (i0 + 1 < Ln) ? xc[i0 + 1] : 0.f;
      }
      #pragma unroll
      for (int sub = 0; sub < 4; ++sub) {
        int pid = lane + (bt * 4 + sub) * 64;
        int r = pid / PPR, p = pid - r * PPR;
        *(unsigned int*)(&Xr[wv][xbuf][r * XRS + 2 * p]) =
            f2bf(a[sub][0]) | (f2bf(a[sub][1]) << 16);
      }
    }
  };

  // snorm: one float4 per thread from prep output
  ((float4*)snormC)[tid] = ((const float4*)snorm)[tid];

  // ---- prologue: per-wave stage c=0; shared xnorm; ONE barrier ----
  stage_b(0);
  stage_x(0, 0);

  // xnorm: 256 threads = 8c x 32 groups, 4 windows each (rolling update), fp32-exact
  {
    int c  = tid >> 5;
    int m0 = (tid & 31) * 4;
    const float* xc = xb + c * Ln;
    auto xq = [&](int i) -> float {
      float v = (i < Ln) ? xc[i] : 0.f;
      return v * v;
    };
    float s0 = 0.f;
    for (int s = 0; s < Sn; ++s) s0 += xq(w0 + m0 + s);
    float s1 = s0 - xq(w0 + m0 + 0) + xq(w0 + m0 + 64);
    float s2 = s1 - xq(w0 + m0 + 1) + xq(w0 + m0 + 65);
    float s3 = s2 - xq(w0 + m0 + 2) + xq(w0 + m0 + 66);
    xnormC[c * WT + m0 + 0] = s0;
    xnormC[c * WT + m0 + 1] = s1;
    xnormC[c * WT + m0 + 2] = s2;
    xnormC[c * WT + m0 + 3] = s3;
  }
  __syncthreads();  // the ONLY barrier: publishes xnorm/snorm (also drains prologue DMA)

  float dist[8][2][4] = {};  // [mtile][nt][reg], this wave's 128w x 32k sub-problem
  int buf = 0;

  for (int c = 0; c < Cn; ++c) {
    // drain this wave's one-phase-old DMA (c's B data); x loads are long consumed
    asm volatile("s_waitcnt vmcnt(0)" ::: "memory");

    // consume B(c) fully into registers (single-buffer discipline)
    short8 bq[2][2];
    const char* bsb = (const char*)&Bs[wv][0];
    #pragma unroll
    for (int nt = 0; nt < 2; ++nt) {
      int rl = nt * 16 + n16;                     // row within the 32-row quarter
      int boff = (rl * 128 + quad * 16) ^ ((rl & 7) << 4);
      bq[nt][0] = *(const short8*)(bsb + boff);
      bq[nt][1] = *(const short8*)(bsb + (boff ^ 64));  // ks=1: +64B, swizzle-safe
    }
    float sn0 = snormC[c * Kn + kq * 32 + n16];
    float sn1 = snormC[c * Kn + kq * 32 + 16 + n16];

    // B reads complete before the overwriting DMA below
    asm volatile("s_waitcnt lgkmcnt(0)" ::: "memory");
    if (c + 1 < Cn) {
      stage_b(c + 1);           // async DMA into same Bs[wv]; drained at next iter top
      stage_x(c + 1, buf ^ 1);  // loads+f2bf+writes; scheduler overlaps with compute
    }

    // compute c: 8 m-tiles x 2 n-tiles, A from this wave's Xr copy
    #pragma unroll
    for (int mt = 0; mt < 8; ++mt) {
      float4 xn = *(const float4*)(&xnormC[c * WT + mt * 16 + quad * 4]);
      int i0 = mt * 16 + n16 + quad * 8;          // ks=0
      short8 a0 = *(const short8*)(&Xr[wv][buf][(i0 & 7) * XRS + (i0 >> 3) * 8]);
      int i1 = i0 + 32;                            // ks=1
      short8 a1 = *(const short8*)(&Xr[wv][buf][(i1 & 7) * XRS + (i1 >> 3) * 8]);
      #pragma unroll
      for (int nt = 0; nt < 2; ++nt) {
        float sn = nt ? sn1 : sn0;
        f32x4 acc;
        #pragma unroll
        for (int rg = 0; rg < 4; ++rg) acc[rg] = xn[rg] + sn;
        acc = __builtin_amdgcn_mfma_f32_16x16x32_bf16(a0, bq[nt][0], acc, 0, 0, 0);
        acc = __builtin_amdgcn_mfma_f32_16x16x32_bf16(a1, bq[nt][1], acc, 0, 0, 0);
        // acc == d2 (norms preloaded in C, -2 folded into B)
        #pragma unroll
        for (int rg = 0; rg < 4; ++rg)
          dist[mt][nt][rg] += __builtin_amdgcn_sqrtf(acc[rg]);
      }
    }
    buf ^= 1;
  }

  // ---- min over windows, then global combine ----
  #pragma unroll
  for (int nt = 0; nt < 2; ++nt) {
    float v = 3.4e38f;
    #pragma unroll
    for (int mt = 0; mt < 8; ++mt)
      #pragma unroll
      for (int rg = 0; rg < 4; ++rg) {
        int wg = w0 + mt * 16 + quad * 4 + rg;
        float d = (wg < Wn) ? dist[mt][nt][rg] : 3.4e38f;
        v = fminf(v, d);
      }
    v = fminf(v, __shfl_xor(v, 16, 64));
    v = fminf(v, __shfl_xor(v, 32, 64));
    if (lane < 16)
      atomicMin(&out[b * Kn + kq * 32 + nt * 16 + n16], __float_as_uint(v));
  }
}

extern "C" void kernel_launch(void* const* d_in, const int* in_sizes, int n_in,
                              void* d_out, int out_size, void* d_ws, size_t ws_size,
                              hipStream_t stream) {
  const float* x  = (const float*)d_in[0];
  const float* sh = (const float*)d_in[1];
  unsigned int* out = (unsigned int*)d_out;
  unsigned short* hbf = (unsigned short*)d_ws;                      // 128 KB
  float* snorm = (float*)((char*)d_ws + (size_t)Cn * Kn * Sn * 2);  // +4 KB
  hipLaunchKernelGGL(prep_kernel, dim3(16), dim3(256), 0, stream, sh, out, hbf, snorm);
  hipLaunchKernelGGL(med_kernel, dim3(NWT, Bn), dim3(BDIM), 0, stream, x, hbf, snorm, out);
}

// Round 14
// 108.474 us; speedup vs baseline: 1.1215x; 1.1215x over previous
//
#include <hip/hip_runtime.h>

// MinEuclideanDistBlock: x(32,8,4096) f32, shapelets(8,128,64) f32 -> out(32,1,128) f32
// out[b,k] = min_w sum_c sqrt( xnorm[b,c,w] + snorm[c,k] - 2*sum_s x[b,c,w+s]*h[c,k,s] )
//
// R15 -> R16 (post-mortem: barrier-free + wave-private staging = 84us (4x x-stage dup,
// conflicts 0.5M->2.1M). Session verdict: occupancy 18-34% all tie at 57-89us ->
// neither barriers nor occupancy nor staging latency is the wall. Issue accounting:
// ~75% per-wave stall with only ~9k cyc issue per 68k cyc lifetime. Last hypothesis:
// ILP starvation - R5/R8's inner loop exposes 1 B-load -> 2 CHAINED MFMA -> 4 sqrt
// per unit, serializing 16 units x 8c of dependency latency):
//  - R8 base (57.0us best; pass-pingpong DMA, 2 barriers/c-iter, async x-stage) with
//    ONLY the pass loop rebuilt: nt processed in PAIRS, 4 independent acc units live;
//    B k-slice-0 pair -> 4 independent MFMA -> k-slice-1 pair -> 4 MFMA -> 16
//    independent sqrt+add. 4 MFMA chains + 16 sqrts in flight vs 1 + 4.
//  - xn re-read per half-pass (16B ds_read, dead after init) caps peak live ~125.
//  - boffB = boffA + 2048 ((ksh+16)&7 == ksh&7): saves the second swizzle calc.
//  - Arithmetic order per element unchanged (init add, k0-MFMA, k1-MFMA, sqrt, acc)
//    -> bit-identical numerics to R8.
//  - Tripwires: WRITE_SIZE >> 2MB = spill (back off to 1-pair live); flat 57us with
//    clean counters = ILP hypothesis refuted -> structural floor.

typedef short short8 __attribute__((ext_vector_type(8)));
typedef float f32x4 __attribute__((ext_vector_type(4)));

constexpr int Bn = 32, Cn = 8, Ln = 4096, Kn = 128, Sn = 64;
constexpr int Wn = Ln - Sn + 1;          // 4033
constexpr int WT = 128;                  // windows per block
constexpr int NWT = (Wn + WT - 1) / WT;  // 32
constexpr int BDIM = 256;

typedef const __attribute__((address_space(1))) unsigned int gas_u32;
typedef __attribute__((address_space(3))) unsigned int las_u32;

__device__ __forceinline__ unsigned int f2bf(float f) {
  unsigned int u = __float_as_uint(f);
  u += 0x7FFFu + ((u >> 16) & 1u);       // round-to-nearest-even
  return u >> 16;
}

// ws layout: [0, 128KB): ushort hbf[C][K][S] = bf16(-2*h), byte-swizzled ^((k&7)<<4)
//            [128KB, +4KB): float snorm[C][K]
__global__ void prep_kernel(const float* __restrict__ sh,
                            unsigned int* __restrict__ out,
                            unsigned short* __restrict__ hbf,
                            float* __restrict__ snorm) {
  int gid = blockIdx.x * blockDim.x + threadIdx.x;  // 0..4095
  out[gid] = 0x7F7FFFFFu;                           // FLT_MAX bits (Bn*Kn == 4096)
  if (gid < Cn * Kn) {
    const float4* row = (const float4*)(sh + (size_t)gid * Sn);
    char* rowb = (char*)hbf + (size_t)gid * (Sn * 2);   // 128B row
    const unsigned int sw = (gid & 7u) << 4;            // (k&7)<<4 byte swizzle
    float a = 0.f;
    #pragma unroll
    for (int i = 0; i < 16; ++i) {
      float4 v = row[i];
      a += v.x * v.x + v.y * v.y + v.z * v.z + v.w * v.w;
      unsigned int p0 = f2bf(-2.f * v.x) | (f2bf(-2.f * v.y) << 16);
      unsigned int p1 = f2bf(-2.f * v.z) | (f2bf(-2.f * v.w) << 16);
      *(uint2*)(rowb + ((8u * i) ^ sw)) = make_uint2(p0, p1);  // stays 8B-aligned
    }
    snorm[gid] = a;
  }
}

__launch_bounds__(BDIM, 2)
__global__ void med_kernel(const float* __restrict__ x,
                           const unsigned short* __restrict__ hbf,
                           const float* __restrict__ snorm,
                           unsigned int* __restrict__ out) {
  constexpr int XRS = 200;  // Xr row stride (elems); 400B, 16B-aligned rows
  __shared__ __align__(16) unsigned short Xr[2][8 * XRS];   // 2 x 3.2KB
  __shared__ __align__(16) unsigned short Bs[2][64 * Sn];   // 2 x 8KB (K-half each)
  __shared__ __align__(16) float xnormC[Cn * WT];           // 4KB
  __shared__ __align__(16) float snormC[Cn * Kn];           // 4KB

  const int tid  = threadIdx.x;
  const int b    = blockIdx.y;
  const int w0   = blockIdx.x * WT;
  const int lane = tid & 63;
  const int wv   = tid >> 6;     // wave 0..3
  const int quad = lane >> 4;    // 0..3
  const int n16  = lane & 15;
  const int wbase = wv * 32;     // this wave's window offset in tile

  const float* xb = x + (size_t)b * Cn * Ln;

  // ---- B staging: linear global->LDS DMA of one pre-swizzled 8KB K-half ----
  auto stage_half = [&](int bufi, int c, int p) {
    const char* src = (const char*)hbf + ((size_t)c * Kn + p * 64) * (Sn * 2);
    char* dst = (char*)&Bs[bufi][0];
    #pragma unroll
    for (int rep = 0; rep < 2; ++rep) {
      int q16 = (tid + rep * BDIM) * 16;   // lane-linear 16B chunks, 0..8191
      __builtin_amdgcn_global_load_lds((gas_u32*)(src + q16), (las_u32*)(dst + q16),
                                       16, 0, 0);
    }
  };

  // ---- X staging: c-invariant index math hoisted; load early / write late ----
  int x_lds[3], x_g[3];
  #pragma unroll
  for (int rep = 0; rep < 3; ++rep) {
    int pid = tid + rep * BDIM;       // 0..767
    int r = pid / 96;
    int p = pid - r * 96;             // pair index 0..95 -> elems 2p,2p+1
    x_lds[rep] = r * XRS + 2 * p;
    x_g[rep] = w0 + r + 2 * p;
  }
  float xf[3][2];
  auto load_x = [&](int c) {
    const float* xc = xb + (size_t)c * Ln;
    #pragma unroll
    for (int rep = 0; rep < 3; ++rep) {
      int i0 = x_g[rep];
      xf[rep][0] = (i0 < Ln) ? xc[i0] : 0.f;
      xf[rep][1] = (i0 + 1 < Ln) ? xc[i0 + 1] : 0.f;
    }
  };
  auto write_x = [&](int bufi) {
    #pragma unroll
    for (int rep = 0; rep < 3; ++rep)
      *(unsigned int*)(&Xr[bufi][x_lds[rep]]) =
          f2bf(xf[rep][0]) | (f2bf(xf[rep][1]) << 16);
  };

  // snorm: one float4 per thread from prep output
  ((float4*)snormC)[tid] = ((const float4*)snorm)[tid];

  // ---- prologue: stage (c=0, pass=0) into Bs[0] (DMA overlaps xnorm compute) ----
  stage_half(0, 0, 0);
  load_x(0);

  // xnorm: 256 threads = 8c x 32 groups, 4 windows each (rolling update), fp32-exact
  {
    int c  = tid >> 5;
    int m0 = (tid & 31) * 4;
    const float* xc = xb + c * Ln;
    auto xq = [&](int i) -> float {
      float v = (i < Ln) ? xc[i] : 0.f;
      return v * v;
    };
    float s0 = 0.f;
    for (int s = 0; s < Sn; ++s) s0 += xq(w0 + m0 + s);
    float s1 = s0 - xq(w0 + m0 + 0) + xq(w0 + m0 + 64);
    float s2 = s1 - xq(w0 + m0 + 1) + xq(w0 + m0 + 65);
    float s3 = s2 - xq(w0 + m0 + 2) + xq(w0 + m0 + 66);
    xnormC[c * WT + m0 + 0] = s0;
    xnormC[c * WT + m0 + 1] = s1;
    xnormC[c * WT + m0 + 2] = s2;
    xnormC[c * WT + m0 + 3] = s3;
  }
  write_x(0);
  __syncthreads();  // drains prologue DMA (implicit vmcnt(0)) + covers norm writes

  float dist[2][8][4] = {};  // [mtile][ntile2][reg] summed distance over c

  for (int c = 0; c < Cn; ++c) {
    const int xbuf = c & 1;

    // ================= phase 0: compute K-half 0, DMA K-half 1 =================
    stage_half(1, c, 1);            // async DMA pass-1 half into Bs[1]
    if (c + 1 < Cn) load_x(c + 1);  // global loads into regs, waited at write_x

    // A fragments: lane m = n16, k = quad*8+j (+ks*32); one aligned b128 each
    short8 af[2][2];
    #pragma unroll
    for (int mt = 0; mt < 2; ++mt)
      #pragma unroll
      for (int ks = 0; ks < 2; ++ks) {
        int i = wbase + mt * 16 + n16 + ks * 32 + quad * 8;
        af[mt][ks] = *(const short8*)(&Xr[xbuf][(i & 7) * XRS + (i >> 3) * 8]);
      }

    #pragma unroll
    for (int pass = 0; pass < 2; ++pass) {
      const char* bsb = (const char*)&Bs[pass][0];
      // nt in PAIRS: 4 independent acc units, 8 MFMA grouped by k-slice,
      // 16 independent sqrts per half-pass.
      #pragma unroll
      for (int hp = 0; hp < 2; ++hp) {
        const int ntA = hp * 2, ntB = ntA + 1;
        const int kshA = ntA * 16 + n16;            // k-row within half: 0..63
        const float snA = snormC[c * Kn + pass * 64 + kshA];
        const float snB = snormC[c * Kn + pass * 64 + kshA + 16];
        const int boffA = (kshA * 128 + quad * 16) ^ ((kshA & 7) << 4);
        const int boffB = boffA + 2048;             // (ksh+16)&7 == ksh&7

        // xn re-read per half-pass (dead after init: caps live regs)
        float4 xn0 = *(const float4*)(&xnormC[c * WT + wbase + quad * 4]);
        float4 xn1 = *(const float4*)(&xnormC[c * WT + wbase + 16 + quad * 4]);

        f32x4 a00, a01, a10, a11;                   // acc[mt][A/B]
        #pragma unroll
        for (int rg = 0; rg < 4; ++rg) {
          a00[rg] = xn0[rg] + snA;
          a01[rg] = xn0[rg] + snB;
          a10[rg] = xn1[rg] + snA;
          a11[rg] = xn1[rg] + snB;
        }

        // k-slice 0: two B frags, 4 independent MFMA
        {
          short8 bA0 = *(const short8*)(bsb + boffA);
          short8 bB0 = *(const short8*)(bsb + boffB);
          a00 = __builtin_amdgcn_mfma_f32_16x16x32_bf16(af[0][0], bA0, a00, 0, 0, 0);
          a01 = __builtin_amdgcn_mfma_f32_16x16x32_bf16(af[0][0], bB0, a01, 0, 0, 0);
          a10 = __builtin_amdgcn_mfma_f32_16x16x32_bf16(af[1][0], bA0, a10, 0, 0, 0);
          a11 = __builtin_amdgcn_mfma_f32_16x16x32_bf16(af[1][0], bB0, a11, 0, 0, 0);
        }
        // k-slice 1: two more B frags, 4 independent MFMA
        {
          short8 bA1 = *(const short8*)(bsb + (boffA ^ 64));  // swizzle-safe +64B
          short8 bB1 = *(const short8*)(bsb + (boffB ^ 64));
          a00 = __builtin_amdgcn_mfma_f32_16x16x32_bf16(af[0][1], bA1, a00, 0, 0, 0);
          a01 = __builtin_amdgcn_mfma_f32_16x16x32_bf16(af[0][1], bB1, a01, 0, 0, 0);
          a10 = __builtin_amdgcn_mfma_f32_16x16x32_bf16(af[1][1], bA1, a10, 0, 0, 0);
          a11 = __builtin_amdgcn_mfma_f32_16x16x32_bf16(af[1][1], bB1, a11, 0, 0, 0);
        }

        // 16 independent sqrts, then accumulate
        #pragma unroll
        for (int rg = 0; rg < 4; ++rg) {
          dist[0][pass * 4 + ntA][rg] += __builtin_amdgcn_sqrtf(a00[rg]);
          dist[0][pass * 4 + ntB][rg] += __builtin_amdgcn_sqrtf(a01[rg]);
          dist[1][pass * 4 + ntA][rg] += __builtin_amdgcn_sqrtf(a10[rg]);
          dist[1][pass * 4 + ntB][rg] += __builtin_amdgcn_sqrtf(a11[rg]);
        }
      }

      if (pass == 0) {
        // barrier 1: publishes Bs[1] (DMA issued a full phase ago); Bs[0] now dead
        __syncthreads();
        // ============ phase 1: compute K-half 1, DMA next c's K-half 0 ============
        if (c + 1 < Cn) stage_half(0, c + 1, 0);
      }
    }

    // late half of async-STAGE: convert + write next x tile into other buffer
    if (c + 1 < Cn) write_x(xbuf ^ 1);
    __syncthreads();  // barrier 2: publishes Xr writes + drains next-c DMA
  }

  // ---- min over windows, then global combine ----
  const int wql = w0 + wbase + quad * 4;
  #pragma unroll
  for (int nt2 = 0; nt2 < 8; ++nt2) {
    float v = 3.4e38f;
    #pragma unroll
    for (int mt = 0; mt < 2; ++mt)
      #pragma unroll
      for (int rg = 0; rg < 4; ++rg) {
        int wg = wql + mt * 16 + rg;
        float d = (wg < Wn) ? dist[mt][nt2][rg] : 3.4e38f;
        v = fminf(v, d);
      }
    v = fminf(v, __shfl_xor(v, 16, 64));
    v = fminf(v, __shfl_xor(v, 32, 64));
    if (lane < 16)
      atomicMin(&out[b * Kn + nt2 * 16 + n16], __float_as_uint(v));
  }
}

extern "C" void kernel_launch(void* const* d_in, const int* in_sizes, int n_in,
                              void* d_out, int out_size, void* d_ws, size_t ws_size,
                              hipStream_t stream) {
  const float* x  = (const float*)d_in[0];
  const float* sh = (const float*)d_in[1];
  unsigned int* out = (unsigned int*)d_out;
  unsigned short* hbf = (unsigned short*)d_ws;                      // 128 KB
  float* snorm = (float*)((char*)d_ws + (size_t)Cn * Kn * Sn * 2);  // +4 KB
  hipLaunchKernelGGL(prep_kernel, dim3(16), dim3(256), 0, stream, sh, out, hbf, snorm);
  hipLaunchKernelGGL(med_kernel, dim3(NWT, Bn), dim3(BDIM), 0, stream, x, hbf, snorm, out);
}

// Round 15
// 105.994 us; speedup vs baseline: 1.1478x; 1.0234x over previous
//
#include <hip/hip_runtime.h>

// MinEuclideanDistBlock: x(32,8,4096) f32, shapelets(8,128,64) f32 -> out(32,1,128) f32
// out[b,k] = min_w sum_c sqrt( xnorm[b,c,w] + snorm[c,k] - 2*sum_s x[b,c,w+s]*h[c,k,s] )
//
// R16 -> R17 (post-mortem: ILP restructure = first win since R3, 57.0->54.4us,
// direction confirmed at 1/5 predicted magnitude. VGPR=88: residency model says
// floor(256/88)=2 waves/SIMD but 85 regs -> 3 waves/SIMD. The untested matrix cell:
// 3 waves/SIMD at CONSTANT work (R13/R14 bought occupancy with duplicated staging).
// Gap is 3 regs, not R4's 35 -> rematerialization, not spill):
//  - __launch_bounds__(256, 3): pins backend budget to 85 (R4-verified).
//  - x_g[3] hoisted array dropped; load_x recomputes r,p from pid (saves exactly 3
//    VGPRs of true demand; ~18 VALU ops/c-iter, noise).
//  - Everything else byte-identical to R16: pass-pingpong DMA, async x-stage,
//    paired-nt inner loop (4 indep MFMA chains, 16 indep sqrts), same arithmetic
//    order -> same numerics.
//  - Tripwires: WRITE_SIZE >> 2MB = spill -> revert to (256,2). Occ up + time flat
//    at constant work = TLP conclusively not the limiter -> declare structural floor.

typedef short short8 __attribute__((ext_vector_type(8)));
typedef float f32x4 __attribute__((ext_vector_type(4)));

constexpr int Bn = 32, Cn = 8, Ln = 4096, Kn = 128, Sn = 64;
constexpr int Wn = Ln - Sn + 1;          // 4033
constexpr int WT = 128;                  // windows per block
constexpr int NWT = (Wn + WT - 1) / WT;  // 32
constexpr int BDIM = 256;

typedef const __attribute__((address_space(1))) unsigned int gas_u32;
typedef __attribute__((address_space(3))) unsigned int las_u32;

__device__ __forceinline__ unsigned int f2bf(float f) {
  unsigned int u = __float_as_uint(f);
  u += 0x7FFFu + ((u >> 16) & 1u);       // round-to-nearest-even
  return u >> 16;
}

// ws layout: [0, 128KB): ushort hbf[C][K][S] = bf16(-2*h), byte-swizzled ^((k&7)<<4)
//            [128KB, +4KB): float snorm[C][K]
__global__ void prep_kernel(const float* __restrict__ sh,
                            unsigned int* __restrict__ out,
                            unsigned short* __restrict__ hbf,
                            float* __restrict__ snorm) {
  int gid = blockIdx.x * blockDim.x + threadIdx.x;  // 0..4095
  out[gid] = 0x7F7FFFFFu;                           // FLT_MAX bits (Bn*Kn == 4096)
  if (gid < Cn * Kn) {
    const float4* row = (const float4*)(sh + (size_t)gid * Sn);
    char* rowb = (char*)hbf + (size_t)gid * (Sn * 2);   // 128B row
    const unsigned int sw = (gid & 7u) << 4;            // (k&7)<<4 byte swizzle
    float a = 0.f;
    #pragma unroll
    for (int i = 0; i < 16; ++i) {
      float4 v = row[i];
      a += v.x * v.x + v.y * v.y + v.z * v.z + v.w * v.w;
      unsigned int p0 = f2bf(-2.f * v.x) | (f2bf(-2.f * v.y) << 16);
      unsigned int p1 = f2bf(-2.f * v.z) | (f2bf(-2.f * v.w) << 16);
      *(uint2*)(rowb + ((8u * i) ^ sw)) = make_uint2(p0, p1);  // stays 8B-aligned
    }
    snorm[gid] = a;
  }
}

__launch_bounds__(BDIM, 3)
__global__ void med_kernel(const float* __restrict__ x,
                           const unsigned short* __restrict__ hbf,
                           const float* __restrict__ snorm,
                           unsigned int* __restrict__ out) {
  constexpr int XRS = 200;  // Xr row stride (elems); 400B, 16B-aligned rows
  __shared__ __align__(16) unsigned short Xr[2][8 * XRS];   // 2 x 3.2KB
  __shared__ __align__(16) unsigned short Bs[2][64 * Sn];   // 2 x 8KB (K-half each)
  __shared__ __align__(16) float xnormC[Cn * WT];           // 4KB
  __shared__ __align__(16) float snormC[Cn * Kn];           // 4KB

  const int tid  = threadIdx.x;
  const int b    = blockIdx.y;
  const int w0   = blockIdx.x * WT;
  const int lane = tid & 63;
  const int wv   = tid >> 6;     // wave 0..3
  const int quad = lane >> 4;    // 0..3
  const int n16  = lane & 15;
  const int wbase = wv * 32;     // this wave's window offset in tile

  const float* xb = x + (size_t)b * Cn * Ln;

  // ---- B staging: linear global->LDS DMA of one pre-swizzled 8KB K-half ----
  auto stage_half = [&](int bufi, int c, int p) {
    const char* src = (const char*)hbf + ((size_t)c * Kn + p * 64) * (Sn * 2);
    char* dst = (char*)&Bs[bufi][0];
    #pragma unroll
    for (int rep = 0; rep < 2; ++rep) {
      int q16 = (tid + rep * BDIM) * 16;   // lane-linear 16B chunks, 0..8191
      __builtin_amdgcn_global_load_lds((gas_u32*)(src + q16), (las_u32*)(dst + q16),
                                       16, 0, 0);
    }
  };

  // ---- X staging: LDS offsets hoisted; global idx recomputed (saves 3 VGPRs) ----
  int x_lds[3];
  #pragma unroll
  for (int rep = 0; rep < 3; ++rep) {
    int pid = tid + rep * BDIM;       // 0..767
    int r = pid / 96;
    int p = pid - r * 96;             // pair index 0..95 -> elems 2p,2p+1
    x_lds[rep] = r * XRS + 2 * p;
  }
  float xf[3][2];
  auto load_x = [&](int c) {
    const float* xc = xb + (size_t)c * Ln;
    #pragma unroll
    for (int rep = 0; rep < 3; ++rep) {
      int pid = tid + rep * BDIM;
      int r = pid / 96;
      int p = pid - r * 96;
      int i0 = w0 + r + 2 * p;
      xf[rep][0] = (i0 < Ln) ? xc[i0] : 0.f;
      xf[rep][1] = (i0 + 1 < Ln) ? xc[i0 + 1] : 0.f;
    }
  };
  auto write_x = [&](int bufi) {
    #pragma unroll
    for (int rep = 0; rep < 3; ++rep)
      *(unsigned int*)(&Xr[bufi][x_lds[rep]]) =
          f2bf(xf[rep][0]) | (f2bf(xf[rep][1]) << 16);
  };

  // snorm: one float4 per thread from prep output
  ((float4*)snormC)[tid] = ((const float4*)snorm)[tid];

  // ---- prologue: stage (c=0, pass=0) into Bs[0] (DMA overlaps xnorm compute) ----
  stage_half(0, 0, 0);
  load_x(0);

  // xnorm: 256 threads = 8c x 32 groups, 4 windows each (rolling update), fp32-exact
  {
    int c  = tid >> 5;
    int m0 = (tid & 31) * 4;
    const float* xc = xb + c * Ln;
    auto xq = [&](int i) -> float {
      float v = (i < Ln) ? xc[i] : 0.f;
      return v * v;
    };
    float s0 = 0.f;
    for (int s = 0; s < Sn; ++s) s0 += xq(w0 + m0 + s);
    float s1 = s0 - xq(w0 + m0 + 0) + xq(w0 + m0 + 64);
    float s2 = s1 - xq(w0 + m0 + 1) + xq(w0 + m0 + 65);
    float s3 = s2 - xq(w0 + m0 + 2) + xq(w0 + m0 + 66);
    xnormC[c * WT + m0 + 0] = s0;
    xnormC[c * WT + m0 + 1] = s1;
    xnormC[c * WT + m0 + 2] = s2;
    xnormC[c * WT + m0 + 3] = s3;
  }
  write_x(0);
  __syncthreads();  // drains prologue DMA (implicit vmcnt(0)) + covers norm writes

  float dist[2][8][4] = {};  // [mtile][ntile2][reg] summed distance over c

  for (int c = 0; c < Cn; ++c) {
    const int xbuf = c & 1;

    // ================= phase 0: compute K-half 0, DMA K-half 1 =================
    stage_half(1, c, 1);            // async DMA pass-1 half into Bs[1]
    if (c + 1 < Cn) load_x(c + 1);  // global loads into regs, waited at write_x

    // A fragments: lane m = n16, k = quad*8+j (+ks*32); one aligned b128 each
    short8 af[2][2];
    #pragma unroll
    for (int mt = 0; mt < 2; ++mt)
      #pragma unroll
      for (int ks = 0; ks < 2; ++ks) {
        int i = wbase + mt * 16 + n16 + ks * 32 + quad * 8;
        af[mt][ks] = *(const short8*)(&Xr[xbuf][(i & 7) * XRS + (i >> 3) * 8]);
      }

    #pragma unroll
    for (int pass = 0; pass < 2; ++pass) {
      const char* bsb = (const char*)&Bs[pass][0];
      // nt in PAIRS: 4 independent acc units, 8 MFMA grouped by k-slice,
      // 16 independent sqrts per half-pass.
      #pragma unroll
      for (int hp = 0; hp < 2; ++hp) {
        const int ntA = hp * 2, ntB = ntA + 1;
        const int kshA = ntA * 16 + n16;            // k-row within half: 0..63
        const float snA = snormC[c * Kn + pass * 64 + kshA];
        const float snB = snormC[c * Kn + pass * 64 + kshA + 16];
        const int boffA = (kshA * 128 + quad * 16) ^ ((kshA & 7) << 4);
        const int boffB = boffA + 2048;             // (ksh+16)&7 == ksh&7

        // xn re-read per half-pass (dead after init: caps live regs)
        float4 xn0 = *(const float4*)(&xnormC[c * WT + wbase + quad * 4]);
        float4 xn1 = *(const float4*)(&xnormC[c * WT + wbase + 16 + quad * 4]);

        f32x4 a00, a01, a10, a11;                   // acc[mt][A/B]
        #pragma unroll
        for (int rg = 0; rg < 4; ++rg) {
          a00[rg] = xn0[rg] + snA;
          a01[rg] = xn0[rg] + snB;
          a10[rg] = xn1[rg] + snA;
          a11[rg] = xn1[rg] + snB;
        }

        // k-slice 0: two B frags, 4 independent MFMA
        {
          short8 bA0 = *(const short8*)(bsb + boffA);
          short8 bB0 = *(const short8*)(bsb + boffB);
          a00 = __builtin_amdgcn_mfma_f32_16x16x32_bf16(af[0][0], bA0, a00, 0, 0, 0);
          a01 = __builtin_amdgcn_mfma_f32_16x16x32_bf16(af[0][0], bB0, a01, 0, 0, 0);
          a10 = __builtin_amdgcn_mfma_f32_16x16x32_bf16(af[1][0], bA0, a10, 0, 0, 0);
          a11 = __builtin_amdgcn_mfma_f32_16x16x32_bf16(af[1][0], bB0, a11, 0, 0, 0);
        }
        // k-slice 1: two more B frags, 4 independent MFMA
        {
          short8 bA1 = *(const short8*)(bsb + (boffA ^ 64));  // swizzle-safe +64B
          short8 bB1 = *(const short8*)(bsb + (boffB ^ 64));
          a00 = __builtin_amdgcn_mfma_f32_16x16x32_bf16(af[0][1], bA1, a00, 0, 0, 0);
          a01 = __builtin_amdgcn_mfma_f32_16x16x32_bf16(af[0][1], bB1, a01, 0, 0, 0);
          a10 = __builtin_amdgcn_mfma_f32_16x16x32_bf16(af[1][1], bA1, a10, 0, 0, 0);
          a11 = __builtin_amdgcn_mfma_f32_16x16x32_bf16(af[1][1], bB1, a11, 0, 0, 0);
        }

        // 16 independent sqrts, then accumulate
        #pragma unroll
        for (int rg = 0; rg < 4; ++rg) {
          dist[0][pass * 4 + ntA][rg] += __builtin_amdgcn_sqrtf(a00[rg]);
          dist[0][pass * 4 + ntB][rg] += __builtin_amdgcn_sqrtf(a01[rg]);
          dist[1][pass * 4 + ntA][rg] += __builtin_amdgcn_sqrtf(a10[rg]);
          dist[1][pass * 4 + ntB][rg] += __builtin_amdgcn_sqrtf(a11[rg]);
        }
      }

      if (pass == 0) {
        // barrier 1: publishes Bs[1] (DMA issued a full phase ago); Bs[0] now dead
        __syncthreads();
        // ============ phase 1: compute K-half 1, DMA next c's K-half 0 ============
        if (c + 1 < Cn) stage_half(0, c + 1, 0);
      }
    }

    // late half of async-STAGE: convert + write next x tile into other buffer
    if (c + 1 < Cn) write_x(xbuf ^ 1);
    __syncthreads();  // barrier 2: publishes Xr writes + drains next-c DMA
  }

  // ---- min over windows, then global combine ----
  const int wql = w0 + wbase + quad * 4;
  #pragma unroll
  for (int nt2 = 0; nt2 < 8; ++nt2) {
    float v = 3.4e38f;
    #pragma unroll
    for (int mt = 0; mt < 2; ++mt)
      #pragma unroll
      for (int rg = 0; rg < 4; ++rg) {
        int wg = wql + mt * 16 + rg;
        float d = (wg < Wn) ? dist[mt][nt2][rg] : 3.4e38f;
        v = fminf(v, d);
      }
    v = fminf(v, __shfl_xor(v, 16, 64));
    v = fminf(v, __shfl_xor(v, 32, 64));
    if (lane < 16)
      atomicMin(&out[b * Kn + nt2 * 16 + n16], __float_as_uint(v));
  }
}

extern "C" void kernel_launch(void* const* d_in, const int* in_sizes, int n_in,
                              void* d_out, int out_size, void* d_ws, size_t ws_size,
                              hipStream_t stream) {
  const float* x  = (const float*)d_in[0];
  const float* sh = (const float*)d_in[1];
  unsigned int* out = (unsigned int*)d_out;
  unsigned short* hbf = (unsigned short*)d_ws;                      // 128 KB
  float* snorm = (float*)((char*)d_ws + (size_t)Cn * Kn * Sn * 2);  // +4 KB
  hipLaunchKernelGGL(prep_kernel, dim3(16), dim3(256), 0, stream, sh, out, hbf, snorm);
  hipLaunchKernelGGL(med_kernel, dim3(NWT, Bn), dim3(BDIM), 0, stream, x, hbf, snorm, out);
}